// Round 12
// baseline (299.701 us; speedup 1.0000x reference)
//
#include <hip/hip_runtime.h>

#define TT 512

typedef _Float16 f16x8 __attribute__((ext_vector_type(8)));
typedef float f32x4 __attribute__((ext_vector_type(4)));

__device__ __forceinline__ float fast_exp2(float v) { return __builtin_amdgcn_exp2f(v); }
__device__ __forceinline__ float fast_rcp(float v)  { return __builtin_amdgcn_rcpf(v); }

__global__ __launch_bounds__(64, 1) void lstm_mfma1w_kernel(
    const float* __restrict__ x,     // [B, T, 1]
    const float* __restrict__ wih,   // [128, 1]
    const float* __restrict__ whh,   // [128, 32]
    const float* __restrict__ bih,   // [128]
    const float* __restrict__ bhh,   // [128]
    const float* __restrict__ fc1w,  // [16, 32]
    const float* __restrict__ fc1b,  // [16]
    const float* __restrict__ fc2w,  // [1, 16]
    const float* __restrict__ fc2b,  // [1]
    float* __restrict__ out)         // [B, 1]
{
    __shared__ float lds_xT[TT + 1][16];   // x transposed [t][batch]; row TT zeroed for prefetch
    __shared__ float lds_hf[16][32];       // final h f32 for MLP head

    const int lane = threadIdx.x;          // single wave per block
    const int b0 = blockIdx.x * 16;
    const int c  = lane & 15;              // batch col (A row / B-C col)
    const int q  = lane >> 4;              // k-group / C row-group

    // ---- stage x transposed into LDS ----
    {
        const int rb = lane >> 2;          // batch 0..15
        const int m  = lane & 3;
        const float4* xr = reinterpret_cast<const float4*>(x + (size_t)(b0 + rb) * TT);
#pragma unroll 4
        for (int it = 0; it < 32; ++it) {
            const int idx = it * 4 + m;
            const float4 v = xr[idx];
            const int t0 = idx * 4;
            lds_xT[t0 + 0][rb] = v.x;
            lds_xT[t0 + 1][rb] = v.y;
            lds_xT[t0 + 2][rb] = v.z;
            lds_xT[t0 + 3][rb] = v.w;
        }
        if (lane < 16) lds_xT[TT][lane] = 0.0f;
    }

    const float NK  = -1.4426950408889634f;   // -log2(e)
    const float NK2 = -2.8853900817779268f;   // -2*log2(e)

    // ---- A fragments with sigma-permuted k-order ----
    // k-position kk holds unit sigma^-1(kk) = (kk>>1) + 16*(kk&1).
    // afrag[n][j]: kk = 8q+j -> unit 4q + (j>>1) + 16*(j&1).
    f16x8 afrag[8];
#pragma unroll
    for (int n = 0; n < 8; ++n) {
        const float s = (n == 4 || n == 5) ? NK2 : NK;
        const float* src = whh + (n * 16 + c) * 32;
        f16x8 a;
#pragma unroll
        for (int j = 0; j < 8; ++j)
            a[j] = (_Float16)(s * src[4 * q + (j >> 1) + 16 * (j & 1)]);
        afrag[n] = a;
    }

    // ---- scaled wih / bias for C-init: gate gg = 16n + 4q + r ----
    float wq[8][4], bq[8][4];
#pragma unroll
    for (int n = 0; n < 8; ++n) {
        const float s = (n == 4 || n == 5) ? NK2 : NK;
#pragma unroll
        for (int r = 0; r < 4; ++r) {
            const int gg = n * 16 + q * 4 + r;
            wq[n][r] = s * wih[gg];
            bq[n][r] = s * (bih[gg] + bhh[gg]);
        }
    }

    // B fragment lives entirely in registers: bfrag[2r+p] = h(unit 4q+r+16p) of col c.
    f16x8 bfrag;
#pragma unroll
    for (int j = 0; j < 8; ++j) bfrag[j] = (_Float16)0.0f;

    float cst[4][2];                       // c-state, unit (r,p) = 4q+r+16p
#pragma unroll
    for (int r = 0; r < 4; ++r) { cst[r][0] = 0.0f; cst[r][1] = 0.0f; }

    // single wave: same-wave DS ordering makes staging visible; no barrier needed
    float xv = lds_xT[0][c];

#pragma unroll 1
    for (int t = 0; t < TT; ++t) {
        f32x4 acc[8];
#pragma unroll
        for (int n = 0; n < 8; ++n) {
            f32x4 ini;
#pragma unroll
            for (int r = 0; r < 4; ++r) ini[r] = __builtin_fmaf(xv, wq[n][r], bq[n][r]);
            acc[n] = __builtin_amdgcn_mfma_f32_16x16x32_f16(afrag[n], bfrag, ini, 0, 0, 0);
        }

        const float xnext = lds_xT[t + 1][c];   // off the critical path

        // 8 cell updates per lane, all register-local; gates of unit (r,p)
        // are acc[{0,2,4,6}+p][r] (pre-scaled by -log2e / -2log2e).
#pragma unroll
        for (int r = 0; r < 4; ++r) {
#pragma unroll
            for (int p = 0; p < 2; ++p) {
                const float ei = fast_exp2(acc[0 + p][r]);
                const float ef = fast_exp2(acc[2 + p][r]);
                const float eg = fast_exp2(acc[4 + p][r]);
                const float eo = fast_exp2(acc[6 + p][r]);
                // c' = (c*(1+ei)(1+eg) + (1-eg)(1+ef)) / ((1+ei)(1+eg)(1+ef))
                const float P  = (1.0f + ei) * (1.0f + eg);
                const float Bf = 1.0f + ef;
                const float N  = __builtin_fmaf(cst[r][p], P, (1.0f - eg) * Bf);
                const float cn = N * fast_rcp(P * Bf);
                cst[r][p] = cn;
                // h = (1-ec) / ((1+ec)(1+eo)),  ec = exp2(-2log2e * c')
                const float ec = fast_exp2(NK2 * cn);
                const float hv = (1.0f - ec) * fast_rcp((1.0f + eo) * (1.0f + ec));
                bfrag[2 * r + p] = (_Float16)hv;   // pure register recurrence
            }
        }

        xv = xnext;
    }

    // ---- final h to LDS for the MLP head: bfrag[j] = unit 4q+(j>>1)+16*(j&1) ----
#pragma unroll
    for (int j = 0; j < 8; ++j)
        lds_hf[c][4 * q + (j >> 1) + 16 * (j & 1)] = (float)bfrag[j];

    // same-wave write->read, in order; no barrier
    const int bat = lane >> 2;             // 4 lanes per batch
    const int mg  = lane & 3;              // each lane: 4 fc1 rows
    float val = 0.0f;
#pragma unroll
    for (int mm = 0; mm < 4; ++mm) {
        const int m = mg * 4 + mm;
        float s = fc1b[m];
        const float* fw = fc1w + m * 32;
#pragma unroll 8
        for (int u = 0; u < 32; ++u) s = __builtin_fmaf(lds_hf[bat][u], fw[u], s);
        val = __builtin_fmaf(fmaxf(s, 0.0f), fc2w[m], val);
    }
    val += __shfl_xor(val, 1);
    val += __shfl_xor(val, 2);
    if (mg == 0) out[b0 + bat] = val + fc2b[0];
}

extern "C" void kernel_launch(void* const* d_in, const int* in_sizes, int n_in,
                              void* d_out, int out_size, void* d_ws, size_t ws_size,
                              hipStream_t stream) {
    const float* x    = (const float*)d_in[0];
    const float* wih  = (const float*)d_in[1];
    const float* whh  = (const float*)d_in[2];
    const float* bih  = (const float*)d_in[3];
    const float* bhh  = (const float*)d_in[4];
    const float* fc1w = (const float*)d_in[5];
    const float* fc1b = (const float*)d_in[6];
    const float* fc2w = (const float*)d_in[7];
    const float* fc2b = (const float*)d_in[8];
    float* out = (float*)d_out;

    const int B = out_size;                // 4096
    dim3 grid(B / 16), block(64);          // 256 one-wave chains, 1 per CU
    hipLaunchKernelGGL(lstm_mfma1w_kernel, grid, block, 0, stream,
                       x, wih, whh, bih, bhh, fc1w, fc1b, fc2w, fc2b, out);
}

// Round 13
// 298.085 us; speedup vs baseline: 1.0054x; 1.0054x over previous
//
#include <hip/hip_runtime.h>

#define TT 512

typedef _Float16 f16x8 __attribute__((ext_vector_type(8)));
typedef float f32x4 __attribute__((ext_vector_type(4)));

__device__ __forceinline__ float fast_exp2(float v) { return __builtin_amdgcn_exp2f(v); }
__device__ __forceinline__ float fast_rcp(float v)  { return __builtin_amdgcn_rcpf(v); }

__global__ __launch_bounds__(64, 1) void lstm_mfma_bf_kernel(
    const float* __restrict__ x,     // [B, T, 1]
    const float* __restrict__ wih,   // [128, 1]
    const float* __restrict__ whh,   // [128, 32]
    const float* __restrict__ bih,   // [128]
    const float* __restrict__ bhh,   // [128]
    const float* __restrict__ fc1w,  // [16, 32]
    const float* __restrict__ fc1b,  // [16]
    const float* __restrict__ fc2w,  // [1, 16]
    const float* __restrict__ fc2b,  // [1]
    float* __restrict__ out)         // [B, 1]
{
    __shared__ float lds_xT[TT + 1][16];   // x transposed [t][batch]; row TT zeroed
    __shared__ float lds_hf[16][32];       // final h f32 for MLP head

    const int lane = threadIdx.x;          // single wave per block
    const int b0 = blockIdx.x * 16;
    const int c  = lane & 15;              // batch col
    const int q  = lane >> 4;              // k-group / C row-group

    // ---- stage x transposed into LDS ----
    {
        const int rb = lane >> 2;
        const int m  = lane & 3;
        const float4* xr = reinterpret_cast<const float4*>(x + (size_t)(b0 + rb) * TT);
#pragma unroll 4
        for (int it = 0; it < 32; ++it) {
            const int idx = it * 4 + m;
            const float4 v = xr[idx];
            const int t0 = idx * 4;
            lds_xT[t0 + 0][rb] = v.x;
            lds_xT[t0 + 1][rb] = v.y;
            lds_xT[t0 + 2][rb] = v.z;
            lds_xT[t0 + 3][rb] = v.w;
        }
        if (lane < 16) lds_xT[TT][lane] = 0.0f;
    }

    const float NK  = -1.4426950408889634f;   // -log2(e)
    const float NK2 = -2.8853900817779268f;   // -2*log2(e)

    // ---- A fragments, sigma-permuted k-order: kk holds unit (kk>>1)+16*(kk&1) ----
    f16x8 afrag[8];
#pragma unroll
    for (int n = 0; n < 8; ++n) {
        const float s = (n == 4 || n == 5) ? NK2 : NK;
        const float* src = whh + (n * 16 + c) * 32;
        f16x8 a;
#pragma unroll
        for (int j = 0; j < 8; ++j)
            a[j] = (_Float16)(s * src[4 * q + (j >> 1) + 16 * (j & 1)]);
        afrag[n] = a;
    }

    // ---- scaled wih / bias: gate gg = 16n + 4q + r ----
    float wq[8][4], bq[8][4];
#pragma unroll
    for (int n = 0; n < 8; ++n) {
        const float s = (n == 4 || n == 5) ? NK2 : NK;
#pragma unroll
        for (int r = 0; r < 4; ++r) {
            const int gg = n * 16 + q * 4 + r;
            wq[n][r] = s * wih[gg];
            bq[n][r] = s * (bih[gg] + bhh[gg]);
        }
    }

    // B fragment in registers: bfrag[2r+p] = h(unit 4q+r+16p) of col c
    f16x8 bfrag;
#pragma unroll
    for (int j = 0; j < 8; ++j) bfrag[j] = (_Float16)0.0f;

    float cst[8];                          // c-state, u = 2r+p -> unit 4q+r+16p
#pragma unroll
    for (int u = 0; u < 8; ++u) cst[u] = 0.0f;

    float xv = lds_xT[0][c];

#pragma unroll 1
    for (int t = 0; t < TT; ++t) {
        // ---- MFMA phase ----
        f32x4 acc[8];
#pragma unroll
        for (int n = 0; n < 8; ++n) {
            f32x4 ini;
#pragma unroll
            for (int r = 0; r < 4; ++r) ini[r] = __builtin_fmaf(xv, wq[n][r], bq[n][r]);
            acc[n] = __builtin_amdgcn_mfma_f32_16x16x32_f16(afrag[n], bfrag, ini, 0, 0, 0);
        }

        const float xnext = lds_xT[t + 1][c];

        // ---- stage A: all 32 gate exp2, breadth-first (independent) ----
        float ei[8], ef[8], eg[8], eo[8];
#pragma unroll
        for (int r = 0; r < 4; ++r) {
#pragma unroll
            for (int p = 0; p < 2; ++p) {
                const int u = 2 * r + p;
                ei[u] = fast_exp2(acc[0 + p][r]);
                ef[u] = fast_exp2(acc[2 + p][r]);
                eg[u] = fast_exp2(acc[4 + p][r]);
                eo[u] = fast_exp2(acc[6 + p][r]);
            }
        }

        // ---- stage B: c' for all units (8-wide ILP) ----
        float cn[8];
#pragma unroll
        for (int u = 0; u < 8; ++u) {
            const float P  = (1.0f + ei[u]) * (1.0f + eg[u]);
            const float Bf = 1.0f + ef[u];
            const float N  = __builtin_fmaf(cst[u], P, (1.0f - eg[u]) * Bf);
            const float v  = N * fast_rcp(P * Bf);
            cst[u] = v;
            cn[u] = v;
        }

        // ---- stage C: tanh exp2 (8 independent) ----
        float ec[8];
#pragma unroll
        for (int u = 0; u < 8; ++u) ec[u] = fast_exp2(NK2 * cn[u]);

        // ---- stage D: h + pack into bfrag words via cvt_pkrtz ----
        float hv[8];
#pragma unroll
        for (int u = 0; u < 8; ++u)
            hv[u] = (1.0f - ec[u]) * fast_rcp((1.0f + eo[u]) * (1.0f + ec[u]));

        uint4 bw;
        bw.x = __builtin_bit_cast(unsigned, __builtin_amdgcn_cvt_pkrtz(hv[0], hv[1]));
        bw.y = __builtin_bit_cast(unsigned, __builtin_amdgcn_cvt_pkrtz(hv[2], hv[3]));
        bw.z = __builtin_bit_cast(unsigned, __builtin_amdgcn_cvt_pkrtz(hv[4], hv[5]));
        bw.w = __builtin_bit_cast(unsigned, __builtin_amdgcn_cvt_pkrtz(hv[6], hv[7]));
        bfrag = __builtin_bit_cast(f16x8, bw);

        xv = xnext;
    }

    // ---- final h to LDS: bfrag[j] = unit 4q+(j>>1)+16*(j&1) of col c ----
#pragma unroll
    for (int j = 0; j < 8; ++j)
        lds_hf[c][4 * q + (j >> 1) + 16 * (j & 1)] = (float)bfrag[j];

    // same-wave write->read, in order; no barrier needed
    const int bat = lane >> 2;
    const int mg  = lane & 3;
    float val = 0.0f;
#pragma unroll
    for (int mm = 0; mm < 4; ++mm) {
        const int m = mg * 4 + mm;
        float s = fc1b[m];
        const float* fw = fc1w + m * 32;
#pragma unroll 8
        for (int u = 0; u < 32; ++u) s = __builtin_fmaf(lds_hf[bat][u], fw[u], s);
        val = __builtin_fmaf(fmaxf(s, 0.0f), fc2w[m], val);
    }
    val += __shfl_xor(val, 1);
    val += __shfl_xor(val, 2);
    if (mg == 0) out[b0 + bat] = val + fc2b[0];
}

extern "C" void kernel_launch(void* const* d_in, const int* in_sizes, int n_in,
                              void* d_out, int out_size, void* d_ws, size_t ws_size,
                              hipStream_t stream) {
    const float* x    = (const float*)d_in[0];
    const float* wih  = (const float*)d_in[1];
    const float* whh  = (const float*)d_in[2];
    const float* bih  = (const float*)d_in[3];
    const float* bhh  = (const float*)d_in[4];
    const float* fc1w = (const float*)d_in[5];
    const float* fc1b = (const float*)d_in[6];
    const float* fc2w = (const float*)d_in[7];
    const float* fc2b = (const float*)d_in[8];
    float* out = (float*)d_out;

    const int B = out_size;                // 4096
    dim3 grid(B / 16), block(64);          // 256 one-wave chains, 1 per CU
    hipLaunchKernelGGL(lstm_mfma_bf_kernel, grid, block, 0, stream,
                       x, wih, whh, bih, bhh, fc1w, fc1b, fc2w, fc2b, out);
}

// Round 14
// 288.082 us; speedup vs baseline: 1.0403x; 1.0347x over previous
//
#include <hip/hip_runtime.h>

#define TT 512

typedef _Float16 f16x8 __attribute__((ext_vector_type(8)));
typedef float f32x4 __attribute__((ext_vector_type(4)));

__device__ __forceinline__ float fast_exp2(float v) { return __builtin_amdgcn_exp2f(v); }
__device__ __forceinline__ float fast_rcp(float v)  { return __builtin_amdgcn_rcpf(v); }

__global__ __launch_bounds__(128, 1) void lstm_mfma2w_kernel(
    const float* __restrict__ x,     // [B, T, 1]
    const float* __restrict__ wih,   // [128, 1]
    const float* __restrict__ whh,   // [128, 32]
    const float* __restrict__ bih,   // [128]
    const float* __restrict__ bhh,   // [128]
    const float* __restrict__ fc1w,  // [16, 32]
    const float* __restrict__ fc1b,  // [16]
    const float* __restrict__ fc2w,  // [1, 16]
    const float* __restrict__ fc2b,  // [1]
    float* __restrict__ out)         // [B, 1]
{
    __shared__ float    lds_xT[TT + 1][16];  // x transposed [t][batch]; row TT zeroed
    __shared__ unsigned lds_h[2][16][20];    // packed f16 h-pairs (u,u+16): [buf][col][word], stride 20
    __shared__ float    lds_hf[16][32];      // final h f32 for MLP head

    const int tid  = threadIdx.x;
    const int wv   = tid >> 6;               // wave 0/1 — owns C rows r = 2wv, 2wv+1
    const int lane = tid & 63;
    const int b0 = blockIdx.x * 16;
    const int c  = lane & 15;                // batch col
    const int q  = lane >> 4;                // k-group / C row-group

    // ---- stage x transposed into LDS (128 threads) ----
    {
        const int rb = tid >> 3;             // batch 0..15
        const int m  = tid & 7;
        const float4* xr = reinterpret_cast<const float4*>(x + (size_t)(b0 + rb) * TT);
#pragma unroll 4
        for (int it = 0; it < 16; ++it) {
            const int idx = it * 8 + m;      // float4 index 0..127
            const float4 v = xr[idx];
            const int t0 = idx * 4;
            lds_xT[t0 + 0][rb] = v.x;
            lds_xT[t0 + 1][rb] = v.y;
            lds_xT[t0 + 2][rb] = v.z;
            lds_xT[t0 + 3][rb] = v.w;
        }
        if (tid < 16) lds_xT[TT][tid] = 0.0f;
        // zero both h buffers (2*16*20 = 640 words)
        unsigned* hz = &lds_h[0][0][0];
        for (int i = tid; i < 640; i += 128) hz[i] = 0u;
    }

    const float NK  = -1.4426950408889634f;  // -log2(e)
    const float NK2 = -2.8853900817779268f;  // -2*log2(e)

    // ---- A fragments, sigma-permuted k-order: kk holds unit (kk>>1)+16*(kk&1) ----
    f16x8 afrag[8];
#pragma unroll
    for (int n = 0; n < 8; ++n) {
        const float s = (n == 4 || n == 5) ? NK2 : NK;
        const float* src = whh + (n * 16 + c) * 32;
        f16x8 a;
#pragma unroll
        for (int j = 0; j < 8; ++j)
            a[j] = (_Float16)(s * src[4 * q + (j >> 1) + 16 * (j & 1)]);
        afrag[n] = a;
    }

    // ---- scaled wih / bias for OWN rows only: gate gg = 16n + 4q + 2wv + rr ----
    float wq2[8][2], bq2[8][2];
#pragma unroll
    for (int n = 0; n < 8; ++n) {
        const float s = (n == 4 || n == 5) ? NK2 : NK;
#pragma unroll
        for (int rr = 0; rr < 2; ++rr) {
            const int gg = n * 16 + q * 4 + 2 * wv + rr;
            wq2[n][rr] = s * wih[gg];
            bq2[n][rr] = s * (bih[gg] + bhh[gg]);
        }
    }

    f16x8 bfrag;
#pragma unroll
    for (int j = 0; j < 8; ++j) bfrag[j] = (_Float16)0.0f;

    float cst[2][2];                         // c-state [rr][p], unit 4q + 2wv+rr + 16p
    cst[0][0] = cst[0][1] = cst[1][0] = cst[1][1] = 0.0f;

    const f32x4 zero4 = {0.0f, 0.0f, 0.0f, 0.0f};

    __syncthreads();                         // x staged + h zeroed
    float xv = lds_xT[0][c];

    // cell update for own row RL (literal), rr slot RR; writes hw[RR]
#define CELL(RR, RL)                                                                      \
    {                                                                                     \
        float hv0, hv1;                                                                   \
        _Pragma("unroll")                                                                 \
        for (int p = 0; p < 2; ++p) {                                                     \
            const float Ai = acc[0 + p][RL] + __builtin_fmaf(xv, wq2[0 + p][RR], bq2[0 + p][RR]); \
            const float Af = acc[2 + p][RL] + __builtin_fmaf(xv, wq2[2 + p][RR], bq2[2 + p][RR]); \
            const float Ag = acc[4 + p][RL] + __builtin_fmaf(xv, wq2[4 + p][RR], bq2[4 + p][RR]); \
            const float Ao = acc[6 + p][RL] + __builtin_fmaf(xv, wq2[6 + p][RR], bq2[6 + p][RR]); \
            const float ei = fast_exp2(Ai);                                               \
            const float ef = fast_exp2(Af);                                               \
            const float eg = fast_exp2(Ag);                                               \
            const float eo = fast_exp2(Ao);                                               \
            const float P  = (1.0f + ei) * (1.0f + eg);                                   \
            const float Bf = 1.0f + ef;                                                   \
            const float N  = __builtin_fmaf(cst[RR][p], P, (1.0f - eg) * Bf);             \
            const float cn = N * fast_rcp(P * Bf);                                        \
            cst[RR][p] = cn;                                                              \
            const float ec = fast_exp2(NK2 * cn);                                         \
            const float hh = (1.0f - ec) * fast_rcp((1.0f + eo) * (1.0f + ec));           \
            if (p == 0) hv0 = hh; else hv1 = hh;                                          \
        }                                                                                 \
        hw[RR] = __builtin_bit_cast(unsigned, __builtin_amdgcn_cvt_pkrtz(hv0, hv1));      \
    }

#pragma unroll 1
    for (int t = 0; t < TT; ++t) {
        f32x4 acc[8];
#pragma unroll
        for (int n = 0; n < 8; ++n)
            acc[n] = __builtin_amdgcn_mfma_f32_16x16x32_f16(afrag[n], bfrag, zero4, 0, 0, 0);

        const float xnext = lds_xT[t + 1][c];

        unsigned hw[2];
        if (wv == 0) { CELL(0, 0) CELL(1, 1) }
        else         { CELL(0, 2) CELL(1, 3) }

        // one b64 write: words 4q+2wv, 4q+2wv+1 of col c (8B aligned)
        *reinterpret_cast<uint2*>(&lds_h[t & 1][c][4 * q + 2 * wv]) = make_uint2(hw[0], hw[1]);

        __syncthreads();

        // one b128 read: words 4q..4q+3 -> bfrag[j] = h(4q+(j>>1)+16*(j&1))
        bfrag = *reinterpret_cast<const f16x8*>(&lds_h[t & 1][c][4 * q]);
        xv = xnext;
    }
#undef CELL

    // ---- MLP head on wave 0 (bfrag = final h after last read) ----
    if (wv == 0) {
#pragma unroll
        for (int j = 0; j < 8; ++j)
            lds_hf[c][4 * q + (j >> 1) + 16 * (j & 1)] = (float)bfrag[j];

        // same-wave write->read, in order; no barrier needed
        const int bat = lane >> 2;
        const int mg  = lane & 3;
        float val = 0.0f;
#pragma unroll
        for (int mm = 0; mm < 4; ++mm) {
            const int m = mg * 4 + mm;
            float s = fc1b[m];
            const float* fw = fc1w + m * 32;
#pragma unroll 8
            for (int u = 0; u < 32; ++u) s = __builtin_fmaf(lds_hf[bat][u], fw[u], s);
            val = __builtin_fmaf(fmaxf(s, 0.0f), fc2w[m], val);
        }
        val += __shfl_xor(val, 1);
        val += __shfl_xor(val, 2);
        if (mg == 0) out[b0 + bat] = val + fc2b[0];
    }
}

extern "C" void kernel_launch(void* const* d_in, const int* in_sizes, int n_in,
                              void* d_out, int out_size, void* d_ws, size_t ws_size,
                              hipStream_t stream) {
    const float* x    = (const float*)d_in[0];
    const float* wih  = (const float*)d_in[1];
    const float* whh  = (const float*)d_in[2];
    const float* bih  = (const float*)d_in[3];
    const float* bhh  = (const float*)d_in[4];
    const float* fc1w = (const float*)d_in[5];
    const float* fc1b = (const float*)d_in[6];
    const float* fc2w = (const float*)d_in[7];
    const float* fc2b = (const float*)d_in[8];
    float* out = (float*)d_out;

    const int B = out_size;                  // 4096
    dim3 grid(B / 16), block(128);           // 256 chains, 1 per CU, 2 waves each
    hipLaunchKernelGGL(lstm_mfma2w_kernel, grid, block, 0, stream,
                       x, wih, whh, bih, bhh, fc1w, fc1b, fc2w, fc2b, out);
}

// Round 15
// 172.519 us; speedup vs baseline: 1.7372x; 1.6699x over previous
//
#include <hip/hip_runtime.h>

#define TT 512

typedef _Float16 f16x8 __attribute__((ext_vector_type(8)));
typedef float f32x4 __attribute__((ext_vector_type(4)));

__device__ __forceinline__ float fast_exp2(float v) { return __builtin_amdgcn_exp2f(v); }
__device__ __forceinline__ float fast_rcp(float v)  { return __builtin_amdgcn_rcpf(v); }

__global__ __launch_bounds__(64, 1) void lstm_ls4_kernel(
    const float* __restrict__ x,     // [B, T, 1]
    const float* __restrict__ wih,   // [128, 1]
    const float* __restrict__ whh,   // [128, 32]
    const float* __restrict__ bih,   // [128]
    const float* __restrict__ bhh,   // [128]
    const float* __restrict__ fc1w,  // [16, 32]
    const float* __restrict__ fc1b,  // [16]
    const float* __restrict__ fc2w,  // [1, 16]
    const float* __restrict__ fc2b,  // [1]
    float* __restrict__ out)         // [B, 1]
{
    __shared__ float lds_xT[TT + 1][4];   // x transposed [t][batch 0..3]; row TT zeroed
    __shared__ float lds_hf[4][32];       // final h f32 for MLP head

    const int lane = threadIdx.x;         // single wave per block
    const int b0 = blockIdx.x * 4;        // 4 real batches per block
    const int c  = lane & 15;             // MFMA col; real batch = c&3
    const int cb = c & 3;
    const int g  = c >> 2;                // col-group 0..3 — owns acc row r == g
    const int q  = lane >> 4;             // k-group / C row-group

    // ---- stage x rows b0..b0+3 transposed into LDS ----
    {
        const int rb = lane >> 4;         // batch 0..3
        const int m  = lane & 15;
        const float4* xr = reinterpret_cast<const float4*>(x + (size_t)(b0 + rb) * TT);
#pragma unroll
        for (int it = 0; it < 8; ++it) {
            const int idx = it * 16 + m;  // float4 index 0..127
            const float4 v = xr[idx];
            const int t0 = idx * 4;
            lds_xT[t0 + 0][rb] = v.x;
            lds_xT[t0 + 1][rb] = v.y;
            lds_xT[t0 + 2][rb] = v.z;
            lds_xT[t0 + 3][rb] = v.w;
        }
        if (lane < 4) lds_xT[TT][lane] = 0.0f;
    }

    const float NK  = -1.4426950408889634f;   // -log2(e)
    const float NK2 = -2.8853900817779268f;   // -2*log2(e)

    // ---- A fragments, GLOBAL sigma k-order: k-slot 8q+2s+p <-> unit 4q+s+16p ----
    f16x8 afrag[8];
#pragma unroll
    for (int n = 0; n < 8; ++n) {
        const float s = (n == 4 || n == 5) ? NK2 : NK;
        const float* src = whh + (n * 16 + c) * 32;
        f16x8 a;
#pragma unroll
        for (int j = 0; j < 8; ++j)
            a[j] = (_Float16)(s * src[4 * q + (j >> 1) + 16 * (j & 1)]);
        afrag[n] = a;
    }

    // ---- scaled wih / bias for OWN gate rows: gg = 16n + 4q + g ----
    float wq[8], bq[8];
#pragma unroll
    for (int n = 0; n < 8; ++n) {
        const float s = (n == 4 || n == 5) ? NK2 : NK;
        const int gg = n * 16 + q * 4 + g;
        wq[n] = s * wih[gg];
        bq[n] = s * (bih[gg] + bhh[gg]);
    }

    // bpermute byte-addresses for bfrag words s=0..3: source lane (c&3) + 4s + 16q
    const int ba0 = 4 * (cb + 0  + 16 * q);
    const int ba1 = 4 * (cb + 4  + 16 * q);
    const int ba2 = 4 * (cb + 8  + 16 * q);
    const int ba3 = 4 * (cb + 12 + 16 * q);

    f16x8 bfrag;
#pragma unroll
    for (int j = 0; j < 8; ++j) bfrag[j] = (_Float16)0.0f;

    float cst0 = 0.0f, cst1 = 0.0f;       // c-state: units 4q+g (p=0), 4q+g+16 (p=1)
    const f32x4 zero4 = {0.0f, 0.0f, 0.0f, 0.0f};
    const bool gl = (g & 1) != 0;
    const bool gh = (g & 2) != 0;

    float xv = lds_xT[0][cb];             // same-wave DS ordering; no barrier needed

#pragma unroll 1
    for (int t = 0; t < TT; ++t) {
        f32x4 acc[8];
#pragma unroll
        for (int n = 0; n < 8; ++n)
            acc[n] = __builtin_amdgcn_mfma_f32_16x16x32_f16(afrag[n], bfrag, zero4, 0, 0, 0);

        const float xnext = lds_xT[t + 1][cb];

        // extract own row r=g from each acc tile (static indices + cndmask tree)
        float v[8];
#pragma unroll
        for (int n = 0; n < 8; ++n) {
            const float lo = gl ? acc[n][1] : acc[n][0];
            const float hi = gl ? acc[n][3] : acc[n][2];
            v[n] = (gh ? hi : lo) + __builtin_fmaf(xv, wq[n], bq[n]);
        }

        // two cell updates: p=0 -> unit 4q+g, p=1 -> unit 4q+g+16
        float hv0, hv1;
#pragma unroll
        for (int p = 0; p < 2; ++p) {
            const float ei = fast_exp2(v[0 + p]);
            const float ef = fast_exp2(v[2 + p]);
            const float eg = fast_exp2(v[4 + p]);
            const float eo = fast_exp2(v[6 + p]);
            const float P  = (1.0f + ei) * (1.0f + eg);
            const float Bf = 1.0f + ef;
            float& cs = p ? cst1 : cst0;
            const float N  = __builtin_fmaf(cs, P, (1.0f - eg) * Bf);
            const float cn = N * fast_rcp(P * Bf);
            cs = cn;
            const float ec = fast_exp2(NK2 * cn);
            const float hh = (1.0f - ec) * fast_rcp((1.0f + eo) * (1.0f + ec));
            if (p == 0) hv0 = hh; else hv1 = hh;
        }

        // pack own word (bfrag slot g) and gather all 4 slots via bpermute
        const int w = (int)__builtin_bit_cast(unsigned, __builtin_amdgcn_cvt_pkrtz(hv0, hv1));
        uint4 bw;
        bw.x = (unsigned)__builtin_amdgcn_ds_bpermute(ba0, w);
        bw.y = (unsigned)__builtin_amdgcn_ds_bpermute(ba1, w);
        bw.z = (unsigned)__builtin_amdgcn_ds_bpermute(ba2, w);
        bw.w = (unsigned)__builtin_amdgcn_ds_bpermute(ba3, w);
        bfrag = __builtin_bit_cast(f16x8, bw);

        xv = xnext;
    }

    // ---- final h to LDS: bfrag[2s+p] = h(unit 4q+s+16p) of batch c&3 ----
    if (c < 4) {
#pragma unroll
        for (int j = 0; j < 8; ++j)
            lds_hf[c][4 * q + (j >> 1) + 16 * (j & 1)] = (float)bfrag[j];
    }

    // same-wave write->read, in order; no barrier needed
    const int bat = lane >> 4;            // 16 lanes per batch
    const int m   = lane & 15;            // fc1 row
    float s = fc1b[m];
    const float* fw = fc1w + m * 32;
#pragma unroll 8
    for (int u = 0; u < 32; ++u) s = __builtin_fmaf(lds_hf[bat][u], fw[u], s);
    float val = fmaxf(s, 0.0f) * fc2w[m];
    val += __shfl_xor(val, 1);
    val += __shfl_xor(val, 2);
    val += __shfl_xor(val, 4);
    val += __shfl_xor(val, 8);
    if (m == 0) out[b0 + bat] = val + fc2b[0];
}

extern "C" void kernel_launch(void* const* d_in, const int* in_sizes, int n_in,
                              void* d_out, int out_size, void* d_ws, size_t ws_size,
                              hipStream_t stream) {
    const float* x    = (const float*)d_in[0];
    const float* wih  = (const float*)d_in[1];
    const float* whh  = (const float*)d_in[2];
    const float* bih  = (const float*)d_in[3];
    const float* bhh  = (const float*)d_in[4];
    const float* fc1w = (const float*)d_in[5];
    const float* fc1b = (const float*)d_in[6];
    const float* fc2w = (const float*)d_in[7];
    const float* fc2b = (const float*)d_in[8];
    float* out = (float*)d_out;

    const int B = out_size;               // 4096
    dim3 grid(B / 4), block(64);          // 1024 one-wave chains -> 1 per SIMD
    hipLaunchKernelGGL(lstm_ls4_kernel, grid, block, 0, stream,
                       x, wih, whh, bih, bhh, fc1w, fc1b, fc2w, fc2b, out);
}

// Round 16
// 171.782 us; speedup vs baseline: 1.7447x; 1.0043x over previous
//
#include <hip/hip_runtime.h>

#define TT 512

typedef _Float16 f16x8 __attribute__((ext_vector_type(8)));
typedef float f32x4 __attribute__((ext_vector_type(4)));
typedef float f32x2 __attribute__((ext_vector_type(2)));

__device__ __forceinline__ float fast_exp2(float v) { return __builtin_amdgcn_exp2f(v); }
__device__ __forceinline__ float fast_rcp(float v)  { return __builtin_amdgcn_rcpf(v); }

__global__ __launch_bounds__(64, 1) void lstm_ls4b_kernel(
    const float* __restrict__ x,     // [B, T, 1]
    const float* __restrict__ wih,   // [128, 1]
    const float* __restrict__ whh,   // [128, 32]
    const float* __restrict__ bih,   // [128]
    const float* __restrict__ bhh,   // [128]
    const float* __restrict__ fc1w,  // [16, 32]
    const float* __restrict__ fc1b,  // [16]
    const float* __restrict__ fc2w,  // [1, 16]
    const float* __restrict__ fc2b,  // [1]
    float* __restrict__ out)         // [B, 1]
{
    __shared__ float lds_xT[TT + 1][4];   // x transposed [t][batch 0..3]; row TT zeroed
    __shared__ float lds_hf[4][32];       // final h f32 for MLP head

    const int lane = threadIdx.x;         // single wave per block
    const int b0 = blockIdx.x * 4;        // 4 real batches per block
    const int c  = lane & 15;             // MFMA col; real batch = c&3
    const int cb = c & 3;
    const int g  = c >> 2;                // col-group 0..3 — owns acc row r == g
    const int q  = lane >> 4;             // k-group / C row-group

    // ---- stage x rows b0..b0+3 transposed into LDS ----
    {
        const int rb = lane >> 4;         // batch 0..3
        const int m  = lane & 15;
        const float4* xr = reinterpret_cast<const float4*>(x + (size_t)(b0 + rb) * TT);
#pragma unroll
        for (int it = 0; it < 8; ++it) {
            const int idx = it * 16 + m;  // float4 index 0..127
            const float4 v = xr[idx];
            const int t0 = idx * 4;
            lds_xT[t0 + 0][rb] = v.x;
            lds_xT[t0 + 1][rb] = v.y;
            lds_xT[t0 + 2][rb] = v.z;
            lds_xT[t0 + 3][rb] = v.w;
        }
        if (lane < 4) lds_xT[TT][lane] = 0.0f;
    }

    const float NK  = -1.4426950408889634f;   // -log2(e)
    const float NK2 = -2.8853900817779268f;   // -2*log2(e)

    // ---- A fragments, GLOBAL sigma k-order: k-slot 8q+2s+p <-> unit 4q+s+16p ----
    f16x8 afrag[8];
#pragma unroll
    for (int n = 0; n < 8; ++n) {
        const float s = (n == 4 || n == 5) ? NK2 : NK;
        const float* src = whh + (n * 16 + c) * 32;
        f16x8 a;
#pragma unroll
        for (int j = 0; j < 8; ++j)
            a[j] = (_Float16)(s * src[4 * q + (j >> 1) + 16 * (j & 1)]);
        afrag[n] = a;
    }

    // ---- scaled wih / bias for OWN gate rows, packed by p: gg = 16(2γ+p) + 4q + g ----
    f32x2 WQ[4], BQ[4];
#pragma unroll
    for (int gt = 0; gt < 4; ++gt) {
        const float s = (gt == 2) ? NK2 : NK;
#pragma unroll
        for (int p = 0; p < 2; ++p) {
            const int gg = (2 * gt + p) * 16 + q * 4 + g;
            WQ[gt][p] = s * wih[gg];
            BQ[gt][p] = s * (bih[gg] + bhh[gg]);
        }
    }

    // bpermute byte-addresses for bfrag words s=0..3: source lane (c&3) + 4s + 16q
    const int ba0 = 4 * (cb + 0  + 16 * q);
    const int ba1 = 4 * (cb + 4  + 16 * q);
    const int ba2 = 4 * (cb + 8  + 16 * q);
    const int ba3 = 4 * (cb + 12 + 16 * q);

    f16x8 bfrag;
#pragma unroll
    for (int j = 0; j < 8; ++j) bfrag[j] = (_Float16)0.0f;

    f32x2 cs = {0.0f, 0.0f};              // c-state: units 4q+g (p=0), 4q+g+16 (p=1)
    const f32x4 zero4 = {0.0f, 0.0f, 0.0f, 0.0f};
    const f32x2 one2 = {1.0f, 1.0f};
    const f32x2 nk2v = {NK2, NK2};
    const bool gl = (g & 1) != 0;
    const bool gh = (g & 2) != 0;

    float xv = lds_xT[0][cb];             // same-wave DS ordering; no barrier needed

#pragma unroll 1
    for (int t = 0; t < TT; ++t) {
        f32x4 acc[8];
#pragma unroll
        for (int n = 0; n < 8; ++n)
            acc[n] = __builtin_amdgcn_mfma_f32_16x16x32_f16(afrag[n], bfrag, zero4, 0, 0, 0);

        const float xnext = lds_xT[t + 1][cb];

        // extract own row r=g from each acc tile (3 cndmask each)
        float ex[8];
#pragma unroll
        for (int n = 0; n < 8; ++n) {
            const float lo = gl ? acc[n][1] : acc[n][0];
            const float hi = gl ? acc[n][3] : acc[n][2];
            ex[n] = gh ? hi : lo;
        }

        // packed gate pre-activations: V[gt] = (p0,p1), already scaled by -log2e / -2log2e
        const f32x2 xv2 = {xv, xv};
        f32x2 Vi = {ex[0], ex[1]}; Vi += xv2 * WQ[0] + BQ[0];
        f32x2 Vf = {ex[2], ex[3]}; Vf += xv2 * WQ[1] + BQ[1];
        f32x2 Vg = {ex[4], ex[5]}; Vg += xv2 * WQ[2] + BQ[2];
        f32x2 Vo = {ex[6], ex[7]}; Vo += xv2 * WQ[3] + BQ[3];

        // packed cell update (p=0,p=1 lanes of f32x2)
        f32x2 Ei, Ef, Eg, Eo;
        Ei[0] = fast_exp2(Vi[0]); Ei[1] = fast_exp2(Vi[1]);
        Ef[0] = fast_exp2(Vf[0]); Ef[1] = fast_exp2(Vf[1]);
        Eg[0] = fast_exp2(Vg[0]); Eg[1] = fast_exp2(Vg[1]);
        Eo[0] = fast_exp2(Vo[0]); Eo[1] = fast_exp2(Vo[1]);

        const f32x2 P  = (one2 + Ei) * (one2 + Eg);
        const f32x2 Bf = one2 + Ef;
        const f32x2 T  = (one2 - Eg) * Bf;
        const f32x2 N  = cs * P + T;          // pk_fma
        const f32x2 D  = P * Bf;
        // combined reciprocal: 1/D0, 1/D1 from one rcp(D0*D1)
        const float rd = fast_rcp(D[0] * D[1]);
        const f32x2 rdv = {rd, rd};
        const f32x2 Ds = {D[1], D[0]};
        const f32x2 cn = N * (rdv * Ds);
        cs = cn;

        f32x2 t6 = nk2v * cn;
        f32x2 Ec;
        Ec[0] = fast_exp2(t6[0]); Ec[1] = fast_exp2(t6[1]);

        const f32x2 den = (one2 + Eo) * (one2 + Ec);
        const float rd2 = fast_rcp(den[0] * den[1]);
        const f32x2 rdv2 = {rd2, rd2};
        const f32x2 dens = {den[1], den[0]};
        const f32x2 hv = (one2 - Ec) * (rdv2 * dens);

        // pack own word (bfrag slot g) and gather all 4 slots via bpermute
        const int w = (int)__builtin_bit_cast(unsigned, __builtin_amdgcn_cvt_pkrtz(hv[0], hv[1]));
        uint4 bw;
        bw.x = (unsigned)__builtin_amdgcn_ds_bpermute(ba0, w);
        bw.y = (unsigned)__builtin_amdgcn_ds_bpermute(ba1, w);
        bw.z = (unsigned)__builtin_amdgcn_ds_bpermute(ba2, w);
        bw.w = (unsigned)__builtin_amdgcn_ds_bpermute(ba3, w);
        bfrag = __builtin_bit_cast(f16x8, bw);

        xv = xnext;
    }

    // ---- final h to LDS: bfrag[2s+p] = h(unit 4q+s+16p) of batch c&3 ----
    if (c < 4) {
#pragma unroll
        for (int j = 0; j < 8; ++j)
            lds_hf[c][4 * q + (j >> 1) + 16 * (j & 1)] = (float)bfrag[j];
    }

    // same-wave write->read, in order; no barrier needed
    const int bat = lane >> 4;            // 16 lanes per batch
    const int m   = lane & 15;            // fc1 row
    float s = fc1b[m];
    const float* fw = fc1w + m * 32;
#pragma unroll 8
    for (int u = 0; u < 32; ++u) s = __builtin_fmaf(lds_hf[bat][u], fw[u], s);
    float val = fmaxf(s, 0.0f) * fc2w[m];
    val += __shfl_xor(val, 1);
    val += __shfl_xor(val, 2);
    val += __shfl_xor(val, 4);
    val += __shfl_xor(val, 8);
    if (m == 0) out[b0 + bat] = val + fc2b[0];
}

extern "C" void kernel_launch(void* const* d_in, const int* in_sizes, int n_in,
                              void* d_out, int out_size, void* d_ws, size_t ws_size,
                              hipStream_t stream) {
    const float* x    = (const float*)d_in[0];
    const float* wih  = (const float*)d_in[1];
    const float* whh  = (const float*)d_in[2];
    const float* bih  = (const float*)d_in[3];
    const float* bhh  = (const float*)d_in[4];
    const float* fc1w = (const float*)d_in[5];
    const float* fc1b = (const float*)d_in[6];
    const float* fc2w = (const float*)d_in[7];
    const float* fc2b = (const float*)d_in[8];
    float* out = (float*)d_out;

    const int B = out_size;               // 4096
    dim3 grid(B / 4), block(64);          // 1024 one-wave chains -> 1 per SIMD
    hipLaunchKernelGGL(lstm_ls4b_kernel, grid, block, 0, stream,
                       x, wih, whh, bih, bhh, fc1w, fc1b, fc2w, fc2b, out);
}